// Round 1
// baseline (240.301 us; speedup 1.0000x reference)
//
#include <hip/hip_runtime.h>
#include <cmath>

#define BB 16
#define CC 512
#define HWH 4096
#define NH 8
#define DK 64
#define PL 128
#define NG 16

__device__ __forceinline__ float wred_sum(float v){
#pragma unroll
  for (int m = 32; m >= 1; m >>= 1) v += __shfl_xor(v, m, 64);
  return v;
}

// ---------------- K1: logits[b,n,hw] = sum_c x[b,c,hw] * cmw[n,c] ----------------
// grid 256 (16 b x 16 tiles of 256 positions), block 256
__global__ __launch_bounds__(256) void k_logits(const float* __restrict__ x,
                                                const float* __restrict__ cmw,
                                                float* __restrict__ e) {
  int b = blockIdx.x >> 4;
  int tile = blockIdx.x & 15;
  int p = tile * 256 + threadIdx.x;
  const float* xb = x + (size_t)b * CC * HWH + p;
  float acc[NH];
#pragma unroll
  for (int n = 0; n < NH; n++) acc[n] = 0.f;
#pragma unroll 4
  for (int c = 0; c < CC; c++) {
    float xv = xb[(size_t)c * HWH];
#pragma unroll
    for (int n = 0; n < NH; n++) acc[n] = fmaf(xv, cmw[n * CC + c], acc[n]);
  }
  float* ob = e + (size_t)b * NH * HWH + p;
#pragma unroll
  for (int n = 0; n < NH; n++) ob[n * HWH] = acc[n];
}

// ---------------- K2: per-(b,n) softmax over 4096; store UNNORMALIZED exp in place.
// meta[0..127]=inv_sum, [128..255]=cx, [256..383]=cy.  grid 128, block 256
__global__ __launch_bounds__(256) void k_softmax(float* __restrict__ e,
                                                 float* __restrict__ meta) {
  __shared__ float sr[4][4];
  int bn = blockIdx.x;
  int t = threadIdx.x;
  float* row = e + (size_t)bn * HWH;
  float v[16];
  float lmax = -1e30f;
#pragma unroll
  for (int i = 0; i < 16; i++) { v[i] = row[t + 256 * i]; lmax = fmaxf(lmax, v[i]); }
#pragma unroll
  for (int m = 32; m >= 1; m >>= 1) lmax = fmaxf(lmax, __shfl_xor(lmax, m, 64));
  if ((t & 63) == 0) sr[0][t >> 6] = lmax;
  __syncthreads();
  lmax = fmaxf(fmaxf(sr[0][0], sr[0][1]), fmaxf(sr[0][2], sr[0][3]));
  float s = 0.f, sc = 0.f, sy = 0.f;
#pragma unroll
  for (int i = 0; i < 16; i++) {
    int idx = t + 256 * i;
    float ev = expf(v[i] - lmax);
    row[idx] = ev;
    s += ev;
    sc += ev * (float)(idx & 63);
    sy += ev * (float)(idx >> 6);
  }
  s = wred_sum(s); sc = wred_sum(sc); sy = wred_sum(sy);
  if ((t & 63) == 0) { sr[1][t >> 6] = s; sr[2][t >> 6] = sc; sr[3][t >> 6] = sy; }
  __syncthreads();
  if (t == 0) {
    s  = sr[1][0] + sr[1][1] + sr[1][2] + sr[1][3];
    sc = sr[2][0] + sr[2][1] + sr[2][2] + sr[2][3];
    sy = sr[3][0] + sr[3][1] + sr[3][2] + sr[3][3];
    meta[bn]       = 1.f / s;
    meta[128 + bn] = sc / (s * 64.f);   // cx
    meta[256 + bn] = sy / (s * 64.f);   // cy
  }
}

// ---------------- K3: partial[g][b][h][c] = sum_{n in chunk g} x[b,c,n]*e[b,h,n]
// grid 256 (b*NG+g), block 512 (thread == channel). LDS transpose staging.
__global__ __launch_bounds__(512) void k_context(const float* __restrict__ x,
                                                 const float* __restrict__ e,
                                                 float* __restrict__ partial) {
  __shared__ float lds[2][512 * 36];
  int b = blockIdx.x >> 4;
  int g = blockIdx.x & (NG - 1);
  int nb = g * 256;
  int t = threadIdx.x;
  const float* xb = x + (size_t)b * CC * HWH;
  const float* eb = e + (size_t)b * NH * HWH + nb;
  float acc[NH];
#pragma unroll
  for (int h = 0; h < NH; h++) acc[h] = 0.f;

  int nn = t & 31;
  int c0 = t >> 5;  // 0..15
  // stage subtile s into buffer buf
  auto stage = [&](int buf, int s) {
    int n0 = nb + s * 32;
    float* dst = &lds[buf][0];
#pragma unroll
    for (int i = 0; i < 32; i++) {
      int c = c0 + 16 * i;
      dst[c * 36 + nn] = xb[(size_t)c * HWH + n0 + nn];
    }
  };
  stage(0, 0);
  for (int s = 0; s < 8; s++) {
    __syncthreads();
    if (s < 7) stage((s + 1) & 1, s + 1);
    const float* lx = &lds[s & 1][t * 36];
    float xv[32];
#pragma unroll
    for (int j = 0; j < 8; j++) {
      float4 f4 = *reinterpret_cast<const float4*>(lx + 4 * j);
      xv[4 * j + 0] = f4.x; xv[4 * j + 1] = f4.y; xv[4 * j + 2] = f4.z; xv[4 * j + 3] = f4.w;
    }
#pragma unroll
    for (int h = 0; h < NH; h++) {
      const float* er = eb + h * HWH + s * 32;  // wave-uniform -> s_load
      float a = acc[h];
#pragma unroll
      for (int k = 0; k < 32; k++) a = fmaf(xv[k], er[k], a);
      acc[h] = a;
    }
  }
  float* pp = partial + (((size_t)g * BB + b) * NH) * CC + t;
#pragma unroll
  for (int h = 0; h < NH; h++) pp[h * CC] = acc[h];
}

// ---------------- K4: per-batch head attention + MLP -> add_term[b][c]
// grid 16, block 512
__global__ __launch_bounds__(512) void k_head(const float* __restrict__ partial,
    const float* __restrict__ meta,
    const float* __restrict__ g_w, const float* __restrict__ g_b,
    const float* __restrict__ k_w, const float* __restrict__ k_b,
    const float* __restrict__ q_w, const float* __restrict__ q_b,
    const float* __restrict__ v_w, const float* __restrict__ v_b,
    const float* __restrict__ aw1, const float* __restrict__ ab1,
    const float* __restrict__ lng, const float* __restrict__ lnb,
    const float* __restrict__ aw2, const float* __restrict__ ab2,
    float* __restrict__ add_term) {
  int b = blockIdx.x;
  int t = threadIdx.x;
  __shared__ float ctx[NH][CC];       // 16 KB
  __shared__ float kqv[3][NH][DK];    // 6 KB
  __shared__ float wgl[NH][NH];
  __shared__ float smn[NH][NH];
  __shared__ float cxl[NH], cyl[NH];
  __shared__ float oc[CC];
  __shared__ float yv[PL];
  __shared__ float red[2];

  if (t < NH) { cxl[t] = meta[128 + b * NH + t]; cyl[t] = meta[256 + b * NH + t]; }
  // context reduce over NG partials, scale by inv_sum
#pragma unroll
  for (int k = t; k < NH * CC; k += 512) {
    int h = k >> 9, c = k & 511;
    float s = 0.f;
#pragma unroll
    for (int gg = 0; gg < NG; gg++)
      s += partial[(((size_t)gg * BB + b) * NH + h) * CC + c];
    ctx[h][c] = s * meta[b * NH + h];
  }
  __syncthreads();

  // geometric position embedding -> wgl = log(clip(relu(emb.g_w+g_b),1e-6))
  if (t < 64) {
    int m = t >> 3, n = t & 7;
    float dx = cxl[m] - cxl[n];
    float dy = cyl[m] - cyl[n];
    float pos[4] = { fmaxf(dx, 0.f), fmaxf(-dx, 0.f), fmaxf(dy, 0.f), fmaxf(-dy, 0.f) };
    float a = g_b[0];
#pragma unroll
    for (int p = 0; p < 4; p++) {
#pragma unroll
      for (int f = 0; f < 8; f++) {
        float dm = expf(-0.8634694098727671f * (float)f);  // 1000^(-f/8)
        float ang = 100.f * pos[p] * dm;
        a = fmaf(sinf(ang), g_w[p * 8 + f], a);
        a = fmaf(cosf(ang), g_w[32 + p * 8 + f], a);
      }
    }
    float wg = fmaxf(a, 0.f);
    wgl[m][n] = logf(fmaxf(wg, 1e-6f));
  }

  // k/q/v projections: thread t does one (h,d) per matrix
  {
    int h = t >> 6, d = t & 63;
    const float* wm[3] = { k_w, q_w, v_w };
    const float* bm[3] = { k_b, q_b, v_b };
#pragma unroll
    for (int mat = 0; mat < 3; mat++) {
      const float* wr = wm[mat] + d * CC;
      float a = 0.f;
#pragma unroll 4
      for (int c = 0; c < CC; c += 4) {
        float4 w4 = *reinterpret_cast<const float4*>(wr + c);
        a = fmaf(w4.x, ctx[h][c + 0], a);
        a = fmaf(w4.y, ctx[h][c + 1], a);
        a = fmaf(w4.z, ctx[h][c + 2], a);
        a = fmaf(w4.w, ctx[h][c + 3], a);
      }
      kqv[mat][h][d] = a + bm[mat][d];
    }
  }
  __syncthreads();

  if (t < 64) {
    int m = t >> 3, n = t & 7;
    float a = 0.f;
#pragma unroll
    for (int d = 0; d < DK; d++) a = fmaf(kqv[0][m][d], kqv[1][n][d], a);
    smn[m][n] = a * 0.125f + wgl[m][n];
  }
  __syncthreads();
  if (t < 8) {  // softmax over m for column n=t
    float mx = -1e30f;
#pragma unroll
    for (int m = 0; m < NH; m++) mx = fmaxf(mx, smn[m][t]);
    float ssum = 0.f; float ex[NH];
#pragma unroll
    for (int m = 0; m < NH; m++) { ex[m] = expf(smn[m][t] - mx); ssum += ex[m]; }
#pragma unroll
    for (int m = 0; m < NH; m++) smn[m][t] = ex[m] / ssum;
  }
  __syncthreads();
  {  // out_ctx[n*64+d]
    int n = t >> 6, d = t & 63;
    float a = 0.f;
#pragma unroll
    for (int m = 0; m < NH; m++) a = fmaf(smn[m][n], kqv[2][m][d], a);
    oc[t] = a;
  }
  __syncthreads();
  if (t < PL) {
    const float* wr = aw1 + t * CC;
    float a = ab1[t];
#pragma unroll 4
    for (int c = 0; c < CC; c += 4) {
      float4 w4 = *reinterpret_cast<const float4*>(wr + c);
      a = fmaf(w4.x, oc[c + 0], a);
      a = fmaf(w4.y, oc[c + 1], a);
      a = fmaf(w4.z, oc[c + 2], a);
      a = fmaf(w4.w, oc[c + 3], a);
    }
    yv[t] = a;
  }
  __syncthreads();
  if (t < 64) {
    float a  = yv[t] + yv[t + 64];
    float sq = yv[t] * yv[t] + yv[t + 64] * yv[t + 64];
    a = wred_sum(a); sq = wred_sum(sq);
    if (t == 0) {
      float mu = a * (1.f / 128.f);
      float var = sq * (1.f / 128.f) - mu * mu;
      red[0] = mu; red[1] = rsqrtf(var + 1e-5f);
    }
  }
  __syncthreads();
  if (t < PL) {
    float yn = (yv[t] - red[0]) * red[1] * lng[t] + lnb[t];
    yv[t] = fmaxf(yn, 0.f);
  }
  __syncthreads();
  {  // add_term[c] = yv . aw2[c,:] + ab2[c]
    int c = t;
    const float* wr = aw2 + c * PL;
    float a = ab2[c];
#pragma unroll 4
    for (int p = 0; p < PL; p += 4) {
      float4 w4 = *reinterpret_cast<const float4*>(wr + p);
      a = fmaf(w4.x, yv[p + 0], a);
      a = fmaf(w4.y, yv[p + 1], a);
      a = fmaf(w4.z, yv[p + 2], a);
      a = fmaf(w4.w, yv[p + 3], a);
    }
    add_term[b * CC + c] = a;
  }
}

// ---------------- K5: out = x + add_term[b][c] broadcast ----------------
__global__ __launch_bounds__(256) void k_add(const float* __restrict__ x,
                                             const float* __restrict__ add_term,
                                             float* __restrict__ out) {
  const float4* x4 = reinterpret_cast<const float4*>(x);
  float4* o4 = reinterpret_cast<float4*>(out);
  const size_t n4 = (size_t)BB * CC * HWH / 4;  // 8388608
  for (size_t i = (size_t)blockIdx.x * 256 + threadIdx.x; i < n4;
       i += (size_t)gridDim.x * 256) {
    float4 v = x4[i];
    float a = add_term[i >> 10];
    v.x += a; v.y += a; v.z += a; v.w += a;
    o4[i] = v;
  }
}

extern "C" void kernel_launch(void* const* d_in, const int* in_sizes, int n_in,
                              void* d_out, int out_size, void* d_ws, size_t ws_size,
                              hipStream_t stream) {
  const float* x   = (const float*)d_in[0];
  const float* cmw = (const float*)d_in[1];
  // d_in[2] conv_mask_b: constant per-head bias -> softmax-invariant, unused
  const float* g_w = (const float*)d_in[3];
  const float* g_b = (const float*)d_in[4];
  const float* k_w = (const float*)d_in[5];
  const float* k_b = (const float*)d_in[6];
  const float* q_w = (const float*)d_in[7];
  const float* q_b = (const float*)d_in[8];
  const float* v_w = (const float*)d_in[9];
  const float* v_b = (const float*)d_in[10];
  const float* aw1 = (const float*)d_in[11];
  const float* ab1 = (const float*)d_in[12];
  const float* lng = (const float*)d_in[13];
  const float* lnb = (const float*)d_in[14];
  const float* aw2 = (const float*)d_in[15];
  const float* ab2 = (const float*)d_in[16];
  float* out = (float*)d_out;
  float* ws = (float*)d_ws;

  float* e        = ws;                                   // [16][8][4096] = 524288
  float* meta     = ws + 524288;                          // 384 (pad to 512)
  float* partial  = ws + 524800;                          // [16][16][8][512] = 1048576
  float* add_term = partial + (size_t)NG * BB * NH * CC;  // [16][512]

  hipLaunchKernelGGL(k_logits,  dim3(256),  dim3(256), 0, stream, x, cmw, e);
  hipLaunchKernelGGL(k_softmax, dim3(128),  dim3(256), 0, stream, e, meta);
  hipLaunchKernelGGL(k_context, dim3(256),  dim3(512), 0, stream, x, e, partial);
  hipLaunchKernelGGL(k_head,    dim3(16),   dim3(512), 0, stream, partial, meta,
                     g_w, g_b, k_w, k_b, q_w, q_b, v_w, v_b,
                     aw1, ab1, lng, lnb, aw2, ab2, add_term);
  hipLaunchKernelGGL(k_add,     dim3(2048), dim3(256), 0, stream, x, add_term, out);
}

// Round 2
// 239.436 us; speedup vs baseline: 1.0036x; 1.0036x over previous
//
#include <hip/hip_runtime.h>
#include <cmath>

#define BB 16
#define CC 512
#define HWH 4096
#define NH 8
#define DK 64
#define PL 128
#define NG 16

__device__ __forceinline__ float wred_sum(float v){
#pragma unroll
  for (int m = 32; m >= 1; m >>= 1) v += __shfl_xor(v, m, 64);
  return v;
}

// ---------------- K1: logits[b,n,hw] = sum_c x[b,c,hw] * cmw[n,c] ----------------
// grid 256 (16 b x 16 tiles of 256 positions), block 256
__global__ __launch_bounds__(256) void k_logits(const float* __restrict__ x,
                                                const float* __restrict__ cmw,
                                                float* __restrict__ e) {
  int b = blockIdx.x >> 4;
  int tile = blockIdx.x & 15;
  int p = tile * 256 + threadIdx.x;
  const float* xb = x + (size_t)b * CC * HWH + p;
  float acc[NH];
#pragma unroll
  for (int n = 0; n < NH; n++) acc[n] = 0.f;
#pragma unroll 4
  for (int c = 0; c < CC; c++) {
    float xv = xb[(size_t)c * HWH];
#pragma unroll
    for (int n = 0; n < NH; n++) acc[n] = fmaf(xv, cmw[n * CC + c], acc[n]);
  }
  float* ob = e + (size_t)b * NH * HWH + p;
#pragma unroll
  for (int n = 0; n < NH; n++) ob[n * HWH] = acc[n];
}

// ---------------- K2: per-(b,n) softmax over 4096; store UNNORMALIZED exp in place.
// meta[0..127]=inv_sum, [128..255]=cx, [256..383]=cy.  grid 128, block 256
__global__ __launch_bounds__(256) void k_softmax(float* __restrict__ e,
                                                 float* __restrict__ meta) {
  __shared__ float sr[4][4];
  int bn = blockIdx.x;
  int t = threadIdx.x;
  float* row = e + (size_t)bn * HWH;
  float v[16];
  float lmax = -1e30f;
#pragma unroll
  for (int i = 0; i < 16; i++) { v[i] = row[t + 256 * i]; lmax = fmaxf(lmax, v[i]); }
#pragma unroll
  for (int m = 32; m >= 1; m >>= 1) lmax = fmaxf(lmax, __shfl_xor(lmax, m, 64));
  if ((t & 63) == 0) sr[0][t >> 6] = lmax;
  __syncthreads();
  lmax = fmaxf(fmaxf(sr[0][0], sr[0][1]), fmaxf(sr[0][2], sr[0][3]));
  float s = 0.f, sc = 0.f, sy = 0.f;
#pragma unroll
  for (int i = 0; i < 16; i++) {
    int idx = t + 256 * i;
    float ev = expf(v[i] - lmax);
    row[idx] = ev;
    s += ev;
    sc += ev * (float)(idx & 63);
    sy += ev * (float)(idx >> 6);
  }
  s = wred_sum(s); sc = wred_sum(sc); sy = wred_sum(sy);
  if ((t & 63) == 0) { sr[1][t >> 6] = s; sr[2][t >> 6] = sc; sr[3][t >> 6] = sy; }
  __syncthreads();
  if (t == 0) {
    s  = sr[1][0] + sr[1][1] + sr[1][2] + sr[1][3];
    sc = sr[2][0] + sr[2][1] + sr[2][2] + sr[2][3];
    sy = sr[3][0] + sr[3][1] + sr[3][2] + sr[3][3];
    meta[bn]       = 1.f / s;
    meta[128 + bn] = sc / (s * 64.f);   // cx
    meta[256 + bn] = sy / (s * 64.f);   // cy
  }
}

// ---------------- K3: context partial over n-chunk g, fused kqv projection.
// pkqv[g][b][j][512] = sum_c (sum_{n in g} x[b,c,n] e[b,h,n]) * w_j[d,c]
// grid 256 (b*NG+g), block 512 (thread == channel). LDS transpose staging.
__global__ __launch_bounds__(512) void k_context(const float* __restrict__ x,
                                                 const float* __restrict__ e,
                                                 const float* __restrict__ k_w,
                                                 const float* __restrict__ q_w,
                                                 const float* __restrict__ v_w,
                                                 float* __restrict__ pkqv) {
  __shared__ float lds[2][512 * 36];
  int b = blockIdx.x >> 4;
  int g = blockIdx.x & (NG - 1);
  int nb = g * 256;
  int t = threadIdx.x;
  const float* xb = x + (size_t)b * CC * HWH;
  const float* eb = e + (size_t)b * NH * HWH + nb;
  float acc[NH];
#pragma unroll
  for (int h = 0; h < NH; h++) acc[h] = 0.f;

  int nn = t & 31;
  int c0 = t >> 5;  // 0..15
  auto stage = [&](int buf, int s) {
    int n0 = nb + s * 32;
    float* dst = &lds[buf][0];
#pragma unroll
    for (int i = 0; i < 32; i++) {
      int c = c0 + 16 * i;
      dst[c * 36 + nn] = xb[(size_t)c * HWH + n0 + nn];
    }
  };
  stage(0, 0);
  for (int s = 0; s < 8; s++) {
    __syncthreads();
    if (s < 7) stage((s + 1) & 1, s + 1);
    const float* lx = &lds[s & 1][t * 36];
    float xv[32];
#pragma unroll
    for (int j = 0; j < 8; j++) {
      float4 f4 = *reinterpret_cast<const float4*>(lx + 4 * j);
      xv[4 * j + 0] = f4.x; xv[4 * j + 1] = f4.y; xv[4 * j + 2] = f4.z; xv[4 * j + 3] = f4.w;
    }
#pragma unroll
    for (int h = 0; h < NH; h++) {
      const float* er = eb + h * HWH + s * 32;  // wave-uniform -> s_load
      float a = acc[h];
#pragma unroll
      for (int k = 0; k < 32; k++) a = fmaf(xv[k], er[k], a);
      acc[h] = a;
    }
  }
  // ---- fused kqv partial projection ----
  __syncthreads();
  float* ctxl = &lds[0][0];   // [NH][512], thread t owns channel c=t
#pragma unroll
  for (int h = 0; h < NH; h++) ctxl[h * 512 + t] = acc[h];
  __syncthreads();
  int h = t >> 6, d = t & 63;
  const float* cl = ctxl + h * 512;
  const float* wm[3] = { k_w, q_w, v_w };
  float* outb = pkqv + ((size_t)(g * BB + b) * 3) * 512 + t;
#pragma unroll
  for (int j = 0; j < 3; j++) {
    const float* wr = wm[j] + d * CC;
    float a = 0.f;
#pragma unroll 8
    for (int c = 0; c < CC; c += 4) {
      float4 w4 = *reinterpret_cast<const float4*>(wr + c);
      a = fmaf(w4.x, cl[c + 0], a);
      a = fmaf(w4.y, cl[c + 1], a);
      a = fmaf(w4.z, cl[c + 2], a);
      a = fmaf(w4.w, cl[c + 3], a);
    }
    outb[(size_t)j * 512] = a;
  }
}

// ---------------- K4a: reduce pkqv, geometry, head softmax, out_ctx ----------------
// grid 16, block 512
__global__ __launch_bounds__(512) void k_attn(const float* __restrict__ pkqv,
    const float* __restrict__ meta,
    const float* __restrict__ g_w, const float* __restrict__ g_b,
    const float* __restrict__ k_b, const float* __restrict__ q_b,
    const float* __restrict__ v_b,
    float* __restrict__ oc_g) {
  int b = blockIdx.x;
  int t = threadIdx.x;
  __shared__ float kq[3][NH * 68];   // padded stride 68 -> conflict-free dot
  __shared__ float smn[NH][NH];
  __shared__ float cxl[NH], cyl[NH];

  if (t < NH) { cxl[t] = meta[128 + b * NH + t]; cyl[t] = meta[256 + b * NH + t]; }
  int h = t >> 6, d = t & 63;
  float inv = meta[b * NH + h];
  const float* bm[3] = { k_b, q_b, v_b };
#pragma unroll
  for (int j = 0; j < 3; j++) {
    const float* pp = pkqv + ((size_t)(b * 3 + j)) * 512 + t;
    float s0 = 0.f, s1 = 0.f, s2 = 0.f, s3 = 0.f;
#pragma unroll
    for (int gg = 0; gg < NG; gg += 4) {
      s0 += pp[(size_t)(gg + 0) * BB * 3 * 512];
      s1 += pp[(size_t)(gg + 1) * BB * 3 * 512];
      s2 += pp[(size_t)(gg + 2) * BB * 3 * 512];
      s3 += pp[(size_t)(gg + 3) * BB * 3 * 512];
    }
    kq[j][h * 68 + d] = (s0 + s1 + s2 + s3) * inv + bm[j][d];
  }
  __syncthreads();

  if (t < 64) {
    int m = t >> 3, n = t & 7;
    // geometry (registers only; same thread computes smn[m][n])
    float dx = cxl[m] - cxl[n];
    float dy = cyl[m] - cyl[n];
    float pos[4] = { fmaxf(dx, 0.f), fmaxf(-dx, 0.f), fmaxf(dy, 0.f), fmaxf(-dy, 0.f) };
    float a = g_b[0];
#pragma unroll
    for (int p = 0; p < 4; p++) {
#pragma unroll
      for (int f = 0; f < 8; f++) {
        float dm = expf(-0.8634694098727671f * (float)f);  // 1000^(-f/8)
        float ang = 100.f * pos[p] * dm;
        a = fmaf(sinf(ang), g_w[p * 8 + f], a);
        a = fmaf(cosf(ang), g_w[32 + p * 8 + f], a);
      }
    }
    float wgl = logf(fmaxf(fmaxf(a, 0.f), 1e-6f));
    float dot = 0.f;
#pragma unroll
    for (int dd = 0; dd < DK; dd++)
      dot = fmaf(kq[0][m * 68 + dd], kq[1][n * 68 + dd], dot);
    smn[m][n] = dot * 0.125f + wgl;
  }
  __syncthreads();
  if (t < 8) {  // softmax over m for column n=t
    float mx = -1e30f;
#pragma unroll
    for (int m = 0; m < NH; m++) mx = fmaxf(mx, smn[m][t]);
    float ssum = 0.f; float ex[NH];
#pragma unroll
    for (int m = 0; m < NH; m++) { ex[m] = expf(smn[m][t] - mx); ssum += ex[m]; }
#pragma unroll
    for (int m = 0; m < NH; m++) smn[m][t] = ex[m] / ssum;
  }
  __syncthreads();
  {  // out_ctx[n*64+d]
    int n = t >> 6;
    float a = 0.f;
#pragma unroll
    for (int m = 0; m < NH; m++) a = fmaf(smn[m][n], kq[2][m * 68 + d], a);
    oc_g[b * 512 + t] = a;
  }
}

// ---------------- K4b: MLP (1x1 -> LN -> ReLU -> 1x1) -> add_term[b][c] ----------------
// grid 16, block 512; split-K x4 on the first GEMV
__global__ __launch_bounds__(512) void k_mlp(const float* __restrict__ oc_g,
    const float* __restrict__ aw1, const float* __restrict__ ab1,
    const float* __restrict__ lng, const float* __restrict__ lnb,
    const float* __restrict__ aw2, const float* __restrict__ ab2,
    float* __restrict__ add_term) {
  int b = blockIdx.x;
  int t = threadIdx.x;
  __shared__ float ocl[512];
  __shared__ float part[4][128];
  __shared__ float yl[PL];
  __shared__ float sr[2][2];
  ocl[t] = oc_g[b * 512 + t];
  __syncthreads();
  int d = t & 127, p = t >> 7;
  {
    const float* wr = aw1 + d * CC + p * 128;
    const float* ol = ocl + p * 128;
    float a = 0.f;
#pragma unroll 8
    for (int c = 0; c < 128; c += 4) {
      float4 w4 = *reinterpret_cast<const float4*>(wr + c);
      a = fmaf(w4.x, ol[c + 0], a);
      a = fmaf(w4.y, ol[c + 1], a);
      a = fmaf(w4.z, ol[c + 2], a);
      a = fmaf(w4.w, ol[c + 3], a);
    }
    part[p][d] = a;
  }
  __syncthreads();
  float y = 0.f;
  if (t < PL) y = part[0][t] + part[1][t] + part[2][t] + part[3][t] + ab1[t];
  {
    float s  = (t < PL) ? y : 0.f;
    float sq = s * y;  // 0 for t>=PL
    s = wred_sum(s); sq = wred_sum(sq);
    if (t < PL && (t & 63) == 0) { sr[0][t >> 6] = s; sr[1][t >> 6] = sq; }
  }
  __syncthreads();
  {
    float mu = (sr[0][0] + sr[0][1]) * (1.f / 128.f);
    float var = (sr[1][0] + sr[1][1]) * (1.f / 128.f) - mu * mu;
    float rstd = rsqrtf(var + 1e-5f);
    if (t < PL) yl[t] = fmaxf((y - mu) * rstd * lng[t] + lnb[t], 0.f);
  }
  __syncthreads();
  {
    const float* wr = aw2 + t * PL;
    float a = ab2[t];
#pragma unroll 8
    for (int pp = 0; pp < PL; pp += 4) {
      float4 w4 = *reinterpret_cast<const float4*>(wr + pp);
      a = fmaf(w4.x, yl[pp + 0], a);
      a = fmaf(w4.y, yl[pp + 1], a);
      a = fmaf(w4.z, yl[pp + 2], a);
      a = fmaf(w4.w, yl[pp + 3], a);
    }
    add_term[b * CC + t] = a;
  }
}

// ---------------- K5: out = x + add_term[b][c] broadcast ----------------
__global__ __launch_bounds__(256) void k_add(const float* __restrict__ x,
                                             const float* __restrict__ add_term,
                                             float* __restrict__ out) {
  const float4* x4 = reinterpret_cast<const float4*>(x);
  float4* o4 = reinterpret_cast<float4*>(out);
  const size_t n4 = (size_t)BB * CC * HWH / 4;  // 8388608
  for (size_t i = (size_t)blockIdx.x * 256 + threadIdx.x; i < n4;
       i += (size_t)gridDim.x * 256) {
    float4 v = x4[i];
    float a = add_term[i >> 10];
    v.x += a; v.y += a; v.z += a; v.w += a;
    o4[i] = v;
  }
}

extern "C" void kernel_launch(void* const* d_in, const int* in_sizes, int n_in,
                              void* d_out, int out_size, void* d_ws, size_t ws_size,
                              hipStream_t stream) {
  const float* x   = (const float*)d_in[0];
  const float* cmw = (const float*)d_in[1];
  // d_in[2] conv_mask_b: constant per-head bias -> softmax-invariant, unused
  const float* g_w = (const float*)d_in[3];
  const float* g_b = (const float*)d_in[4];
  const float* k_w = (const float*)d_in[5];
  const float* k_b = (const float*)d_in[6];
  const float* q_w = (const float*)d_in[7];
  const float* q_b = (const float*)d_in[8];
  const float* v_w = (const float*)d_in[9];
  const float* v_b = (const float*)d_in[10];
  const float* aw1 = (const float*)d_in[11];
  const float* ab1 = (const float*)d_in[12];
  const float* lng = (const float*)d_in[13];
  const float* lnb = (const float*)d_in[14];
  const float* aw2 = (const float*)d_in[15];
  const float* ab2 = (const float*)d_in[16];
  float* out = (float*)d_out;
  float* ws = (float*)d_ws;

  float* e        = ws;                       // [16][8][4096] = 524288
  float* meta     = ws + 524288;              // 384 (pad to 512)
  float* pkqv     = ws + 524800;              // [16][16][3][512] = 393216
  float* oc_g     = pkqv + 393216;            // [16][512] = 8192
  float* add_term = oc_g + 8192;              // [16][512] = 8192

  hipLaunchKernelGGL(k_logits,  dim3(256),  dim3(256), 0, stream, x, cmw, e);
  hipLaunchKernelGGL(k_softmax, dim3(128),  dim3(256), 0, stream, e, meta);
  hipLaunchKernelGGL(k_context, dim3(256),  dim3(512), 0, stream, x, e, k_w, q_w, v_w, pkqv);
  hipLaunchKernelGGL(k_attn,    dim3(16),   dim3(512), 0, stream, pkqv, meta,
                     g_w, g_b, k_b, q_b, v_b, oc_g);
  hipLaunchKernelGGL(k_mlp,     dim3(16),   dim3(512), 0, stream, oc_g,
                     aw1, ab1, lng, lnb, aw2, ab2, add_term);
  hipLaunchKernelGGL(k_add,     dim3(2048), dim3(256), 0, stream, x, add_term, out);
}

// Round 3
// 150.286 us; speedup vs baseline: 1.5990x; 1.5932x over previous
//
#include <hip/hip_runtime.h>
#include <cmath>

#define BB 16
#define CC 512
#define HWH 4096
#define NH 8
#define DK 64
#define PL 128

__device__ __forceinline__ float wred_sum(float v){
#pragma unroll
  for (int m = 32; m >= 1; m >>= 1) v += __shfl_xor(v, m, 64);
  return v;
}

// ---------------- K1: partial logits, c-split x2 ----------------
// epart[cc][b][n][p] = sum_{c in chunk cc} x[b,c,p] * cmw[n,c]
// grid 512 = b(16) x ptile(16) x cc(2), block 256
__global__ __launch_bounds__(256) void k_logits(const float* __restrict__ x,
                                                const float* __restrict__ cmw,
                                                float* __restrict__ epart) {
  int bid = blockIdx.x;
  int cc = bid & 1;
  int tile = (bid >> 1) & 15;
  int b = bid >> 5;
  int p = tile * 256 + threadIdx.x;
  const float* xb = x + ((size_t)(b * CC + cc * 256)) * HWH + p;
  const float* wb = cmw + cc * 256;
  float acc[NH];
#pragma unroll
  for (int n = 0; n < NH; n++) acc[n] = 0.f;
#pragma unroll 8
  for (int c = 0; c < 256; c++) {
    float xv = xb[(size_t)c * HWH];
#pragma unroll
    for (int n = 0; n < NH; n++) acc[n] = fmaf(xv, wb[n * CC + c], acc[n]);
  }
  float* ob = epart + (((size_t)(cc * BB + b)) * NH) * HWH + p;
#pragma unroll
  for (int n = 0; n < NH; n++) ob[(size_t)n * HWH] = acc[n];
}

// ---------------- K2: sum partials + per-(b,n) softmax over 4096 ----------------
// stores UNNORMALIZED exp into e; meta[0..127]=inv_sum,[128..255]=cx,[256..383]=cy
// grid 128, block 256
__global__ __launch_bounds__(256) void k_softmax(const float* __restrict__ epart,
                                                 float* __restrict__ e,
                                                 float* __restrict__ meta) {
  __shared__ float sr[4][4];
  int bn = blockIdx.x;
  int t = threadIdx.x;
  const float* r0 = epart + (size_t)bn * HWH;
  const float* r1 = r0 + (size_t)BB * NH * HWH;
  float* row = e + (size_t)bn * HWH;
  float v[16];
  float lmax = -1e30f;
#pragma unroll
  for (int i = 0; i < 16; i++) {
    int idx = t + 256 * i;
    v[i] = r0[idx] + r1[idx];
    lmax = fmaxf(lmax, v[i]);
  }
#pragma unroll
  for (int m = 32; m >= 1; m >>= 1) lmax = fmaxf(lmax, __shfl_xor(lmax, m, 64));
  if ((t & 63) == 0) sr[0][t >> 6] = lmax;
  __syncthreads();
  lmax = fmaxf(fmaxf(sr[0][0], sr[0][1]), fmaxf(sr[0][2], sr[0][3]));
  float s = 0.f, sc = 0.f, sy = 0.f;
#pragma unroll
  for (int i = 0; i < 16; i++) {
    int idx = t + 256 * i;
    float ev = expf(v[i] - lmax);
    row[idx] = ev;
    s += ev;
    sc += ev * (float)(idx & 63);
    sy += ev * (float)(idx >> 6);
  }
  s = wred_sum(s); sc = wred_sum(sc); sy = wred_sum(sy);
  if ((t & 63) == 0) { sr[1][t >> 6] = s; sr[2][t >> 6] = sc; sr[3][t >> 6] = sy; }
  __syncthreads();
  if (t == 0) {
    s  = sr[1][0] + sr[1][1] + sr[1][2] + sr[1][3];
    sc = sr[2][0] + sr[2][1] + sr[2][2] + sr[2][3];
    sy = sr[3][0] + sr[3][1] + sr[3][2] + sr[3][3];
    meta[bn]       = 1.f / s;
    meta[128 + bn] = sc / (s * 64.f);   // cx
    meta[256 + bn] = sy / (s * 64.f);   // cy
  }
}

// ---------------- K3: context, register-only. ----------------
// pctx[ng][b][h][c] = sum_{n in half ng} x[b,c,n] * e[b,h,n]
// grid 512 = b(16) x cg(16) x ng(2), block 512 = 8 waves.
// wave w owns channels cg*32+w*4 .. +3; lanes own n (float4, coalesced).
__global__ __launch_bounds__(512) void k_context(const float* __restrict__ x,
                                                 const float* __restrict__ e,
                                                 float* __restrict__ pctx) {
  int bid = blockIdx.x;
  int ng = bid & 1;
  int cg = (bid >> 1) & 15;
  int b = bid >> 5;
  int w = threadIdx.x >> 6;
  int l = threadIdx.x & 63;
  int cbase = cg * 32 + w * 4;
  const float* xb = x + ((size_t)(b * CC + cbase)) * HWH + ng * 2048 + l * 4;
  const float* eb = e + (size_t)b * NH * HWH + ng * 2048 + l * 4;
  float acc[4][NH];
#pragma unroll
  for (int ci = 0; ci < 4; ci++)
#pragma unroll
    for (int h = 0; h < NH; h++) acc[ci][h] = 0.f;

#pragma unroll 2
  for (int ch = 0; ch < 8; ch++) {   // 8 chunks of 256 n
    int off = ch * 256;
    float4 ev[NH];
#pragma unroll
    for (int h = 0; h < NH; h++)
      ev[h] = *reinterpret_cast<const float4*>(eb + (size_t)h * HWH + off);
#pragma unroll
    for (int ci = 0; ci < 4; ci++) {
      float4 xv = *reinterpret_cast<const float4*>(xb + (size_t)ci * HWH + off);
#pragma unroll
      for (int h = 0; h < NH; h++) {
        float a = acc[ci][h];
        a = fmaf(xv.x, ev[h].x, a);
        a = fmaf(xv.y, ev[h].y, a);
        a = fmaf(xv.z, ev[h].z, a);
        a = fmaf(xv.w, ev[h].w, a);
        acc[ci][h] = a;
      }
    }
  }
  // butterfly reduce each accumulator across the 64 lanes
#pragma unroll
  for (int ci = 0; ci < 4; ci++)
#pragma unroll
    for (int h = 0; h < NH; h++) acc[ci][h] = wred_sum(acc[ci][h]);
  if (l == 0) {
    float* op = pctx + (((size_t)(ng * BB + b)) * NH) * CC + cbase;
#pragma unroll
    for (int h = 0; h < NH; h++)
#pragma unroll
      for (int ci = 0; ci < 4; ci++) op[h * CC + ci] = acc[ci][h];
  }
}

// ---------------- K4: kqv projections, 8-way split dots ----------------
// grid 384 = b(16) x j(3) x h(8), block 512
__global__ __launch_bounds__(512) void k_kqv(const float* __restrict__ pctx,
    const float* __restrict__ meta,
    const float* __restrict__ k_w, const float* __restrict__ q_w,
    const float* __restrict__ v_w,
    const float* __restrict__ k_b, const float* __restrict__ q_b,
    const float* __restrict__ v_b,
    float* __restrict__ kqvbuf) {
  int bid = blockIdx.x;
  int b = bid / 24;
  int r = bid - b * 24;
  int j = r >> 3;
  int h = r & 7;
  int t = threadIdx.x;
  __shared__ float ctx[8 * 68];      // padded segments -> conflict-free reads
  __shared__ float psum[64][9];
  float inv = meta[b * NH + h];
  size_t base = ((size_t)b * NH + h) * CC + t;
  float cval = (pctx[base] + pctx[(size_t)BB * NH * CC + base]) * inv;
  ctx[(t >> 6) * 68 + (t & 63)] = cval;
  __syncthreads();
  const float* wm = (j == 0) ? k_w : (j == 1) ? q_w : v_w;
  const float* bm = (j == 0) ? k_b : (j == 1) ? q_b : v_b;
  int d = t >> 3, s = t & 7;
  const float* wr = wm + d * CC + s * 64;
  const float* cl = ctx + s * 68;    // seg s holds channels s*64..s*64+63
  float a = 0.f;
#pragma unroll
  for (int c = 0; c < 64; c += 4) {
    float4 w4 = *reinterpret_cast<const float4*>(wr + c);
    a = fmaf(w4.x, cl[c + 0], a);
    a = fmaf(w4.y, cl[c + 1], a);
    a = fmaf(w4.z, cl[c + 2], a);
    a = fmaf(w4.w, cl[c + 3], a);
  }
  psum[d][s] = a;
  __syncthreads();
  if (t < 64) {
    float rsum = 0.f;
#pragma unroll
    for (int ss = 0; ss < 8; ss++) rsum += psum[t][ss];
    kqvbuf[((size_t)(b * 3 + j) * NH + h) * DK + t] = rsum + bm[t];
  }
}

// ---------------- K5: geometry + head softmax + out_ctx + MLP ----------------
// grid 16, block 512
__global__ __launch_bounds__(512) void k_attn_mlp(const float* __restrict__ kqvbuf,
    const float* __restrict__ meta,
    const float* __restrict__ g_w, const float* __restrict__ g_b,
    const float* __restrict__ aw1, const float* __restrict__ ab1,
    const float* __restrict__ lng, const float* __restrict__ lnb,
    const float* __restrict__ aw2, const float* __restrict__ ab2,
    float* __restrict__ add_term) {
  int b = blockIdx.x;
  int t = threadIdx.x;
  __shared__ float kq[3][NH * 68];
  __shared__ float smn[NH][NH];
  __shared__ float cxl[NH], cyl[NH];
  __shared__ float oc[CC];
  __shared__ float part[4][PL];
  __shared__ float yl[PL];
  __shared__ float sr[2][2];

  if (t < NH) { cxl[t] = meta[128 + b * NH + t]; cyl[t] = meta[256 + b * NH + t]; }
  {
    int h = t >> 6, d = t & 63;
#pragma unroll
    for (int j = 0; j < 3; j++)
      kq[j][h * 68 + d] = kqvbuf[(size_t)(b * 3 + j) * 512 + t];
  }
  __syncthreads();

  if (t < 64) {
    int m = t >> 3, n = t & 7;
    float dx = cxl[m] - cxl[n];
    float dy = cyl[m] - cyl[n];
    float pos[4] = { fmaxf(dx, 0.f), fmaxf(-dx, 0.f), fmaxf(dy, 0.f), fmaxf(-dy, 0.f) };
    float a = g_b[0];
#pragma unroll
    for (int p = 0; p < 4; p++) {
#pragma unroll
      for (int f = 0; f < 8; f++) {
        float dm = expf(-0.8634694098727671f * (float)f);  // 1000^(-f/8)
        float ang = 100.f * pos[p] * dm;
        a = fmaf(sinf(ang), g_w[p * 8 + f], a);
        a = fmaf(cosf(ang), g_w[32 + p * 8 + f], a);
      }
    }
    float wgl = logf(fmaxf(fmaxf(a, 0.f), 1e-6f));
    float dot = 0.f;
#pragma unroll
    for (int dd = 0; dd < DK; dd++)
      dot = fmaf(kq[0][m * 68 + dd], kq[1][n * 68 + dd], dot);
    smn[m][n] = dot * 0.125f + wgl;
  }
  __syncthreads();
  if (t < 8) {  // softmax over m for column n=t
    float mx = -1e30f;
#pragma unroll
    for (int m = 0; m < NH; m++) mx = fmaxf(mx, smn[m][t]);
    float ssum = 0.f; float ex[NH];
#pragma unroll
    for (int m = 0; m < NH; m++) { ex[m] = expf(smn[m][t] - mx); ssum += ex[m]; }
#pragma unroll
    for (int m = 0; m < NH; m++) smn[m][t] = ex[m] / ssum;
  }
  __syncthreads();
  {  // out_ctx[n*64+d]
    int n = t >> 6, d = t & 63;
    float a = 0.f;
#pragma unroll
    for (int m = 0; m < NH; m++) a = fmaf(smn[m][n], kq[2][m * 68 + d], a);
    oc[t] = a;
  }
  __syncthreads();
  {  // MLP layer 1, split-K x4
    int d = t & 127, p = t >> 7;
    const float* wr = aw1 + d * CC + p * 128;
    const float* ol = oc + p * 128;
    float a = 0.f;
#pragma unroll 8
    for (int c = 0; c < 128; c += 4) {
      float4 w4 = *reinterpret_cast<const float4*>(wr + c);
      a = fmaf(w4.x, ol[c + 0], a);
      a = fmaf(w4.y, ol[c + 1], a);
      a = fmaf(w4.z, ol[c + 2], a);
      a = fmaf(w4.w, ol[c + 3], a);
    }
    part[p][d] = a;
  }
  __syncthreads();
  float y = 0.f;
  if (t < PL) y = part[0][t] + part[1][t] + part[2][t] + part[3][t] + ab1[t];
  {
    float s  = (t < PL) ? y : 0.f;
    float sq = s * y;
    s = wred_sum(s); sq = wred_sum(sq);
    if (t < PL && (t & 63) == 0) { sr[0][t >> 6] = s; sr[1][t >> 6] = sq; }
  }
  __syncthreads();
  {
    float mu = (sr[0][0] + sr[0][1]) * (1.f / 128.f);
    float var = (sr[1][0] + sr[1][1]) * (1.f / 128.f) - mu * mu;
    float rstd = rsqrtf(var + 1e-5f);
    if (t < PL) yl[t] = fmaxf((y - mu) * rstd * lng[t] + lnb[t], 0.f);
  }
  __syncthreads();
  {  // MLP layer 2: add_term[c] = yl . aw2[c,:] + ab2[c]
    const float* wr = aw2 + t * PL;
    float a = ab2[t];
#pragma unroll 8
    for (int pp = 0; pp < PL; pp += 4) {
      float4 w4 = *reinterpret_cast<const float4*>(wr + pp);
      a = fmaf(w4.x, yl[pp + 0], a);
      a = fmaf(w4.y, yl[pp + 1], a);
      a = fmaf(w4.z, yl[pp + 2], a);
      a = fmaf(w4.w, yl[pp + 3], a);
    }
    add_term[b * CC + t] = a;
  }
}

// ---------------- K6: out = x + add_term[b][c] broadcast ----------------
__global__ __launch_bounds__(256) void k_add(const float* __restrict__ x,
                                             const float* __restrict__ add_term,
                                             float* __restrict__ out) {
  const float4* x4 = reinterpret_cast<const float4*>(x);
  float4* o4 = reinterpret_cast<float4*>(out);
  const size_t n4 = (size_t)BB * CC * HWH / 4;  // 8388608
  for (size_t i = (size_t)blockIdx.x * 256 + threadIdx.x; i < n4;
       i += (size_t)gridDim.x * 256) {
    float4 v = x4[i];
    float a = add_term[i >> 10];
    v.x += a; v.y += a; v.z += a; v.w += a;
    o4[i] = v;
  }
}

extern "C" void kernel_launch(void* const* d_in, const int* in_sizes, int n_in,
                              void* d_out, int out_size, void* d_ws, size_t ws_size,
                              hipStream_t stream) {
  const float* x   = (const float*)d_in[0];
  const float* cmw = (const float*)d_in[1];
  // d_in[2] conv_mask_b: per-head constant -> softmax-invariant, unused
  const float* g_w = (const float*)d_in[3];
  const float* g_b = (const float*)d_in[4];
  const float* k_w = (const float*)d_in[5];
  const float* k_b = (const float*)d_in[6];
  const float* q_w = (const float*)d_in[7];
  const float* q_b = (const float*)d_in[8];
  const float* v_w = (const float*)d_in[9];
  const float* v_b = (const float*)d_in[10];
  const float* aw1 = (const float*)d_in[11];
  const float* ab1 = (const float*)d_in[12];
  const float* lng = (const float*)d_in[13];
  const float* lnb = (const float*)d_in[14];
  const float* aw2 = (const float*)d_in[15];
  const float* ab2 = (const float*)d_in[16];
  float* out = (float*)d_out;
  float* ws = (float*)d_ws;

  // layout (floats). epart region is dead after k_softmax -> reused for
  // pctx/kqvbuf/add_term. Peak = 1,573,376 floats ~= 6.3 MB.
  float* epart    = ws;                 // [2][16][8][4096] = 1,048,576
  float* e        = ws + 1048576;       // [16][8][4096]    =   524,288
  float* meta     = ws + 1572864;       // 384 (pad 512)
  float* pctx     = ws;                 // [2][16][8][512]  =   131,072 (alias epart)
  float* kqvbuf   = ws + 131072;        // [16][3][8][64]   =    24,576 (alias epart)
  float* add_term = ws + 155648;        // [16][512]        =     8,192 (alias epart)

  hipLaunchKernelGGL(k_logits,   dim3(512),  dim3(256), 0, stream, x, cmw, epart);
  hipLaunchKernelGGL(k_softmax,  dim3(128),  dim3(256), 0, stream, epart, e, meta);
  hipLaunchKernelGGL(k_context,  dim3(512),  dim3(512), 0, stream, x, e, pctx);
  hipLaunchKernelGGL(k_kqv,      dim3(384),  dim3(512), 0, stream, pctx, meta,
                     k_w, q_w, v_w, k_b, q_b, v_b, kqvbuf);
  hipLaunchKernelGGL(k_attn_mlp, dim3(16),   dim3(512), 0, stream, kqvbuf, meta,
                     g_w, g_b, aw1, ab1, lng, lnb, aw2, ab2, add_term);
  hipLaunchKernelGGL(k_add,      dim3(2048), dim3(256), 0, stream, x, add_term, out);
}